// Round 17
// baseline (210.490 us; speedup 1.0000x reference)
//
#include <hip/hip_runtime.h>
#include <hip/hip_bf16.h>

#define NN 100000
#define NE 1600000
#define NG 256
#define FIN 100
#define HH 64

#define BSHIFT 7
#define BSIZE 128
#define NBUCK ((NN + BSIZE - 1) / BSIZE)   // 782
#define BCAP 2560                          // mean 2046 + ~11 sigma
#define CHUNK 4096
#define NPLACE ((NE + CHUNK - 1) / CHUNK)  // 391

#define NBLK64 ((NN + 63) / 64)            // 1563
#define AGGB (NN / 32)                     // 3125

#define SXE 136
#define SH 72

typedef __attribute__((ext_vector_type(8))) short short8;
typedef __attribute__((ext_vector_type(4))) float f32x4;

__device__ __forceinline__ float relu_f(float x){ return x > 0.f ? x : 0.f; }
__device__ __forceinline__ unsigned short f2b(float f) {
    unsigned int u = __float_as_uint(f);
    u += 0x7fffu + ((u >> 16) & 1u);
    return (unsigned short)(u >> 16);
}
__device__ __forceinline__ unsigned pk2(float a, float b) {
    return (unsigned)f2b(a) | ((unsigned)f2b(b) << 16);
}
__device__ __forceinline__ float b2f(unsigned short h) {
    return __uint_as_float(((unsigned int)h) << 16);
}
__device__ __forceinline__ float lo32(unsigned u){ return __uint_as_float(u << 16); }
__device__ __forceinline__ float hi32(unsigned u){ return __uint_as_float(u & 0xffff0000u); }

#define ACC8(U) { a0 += lo32(U.x); a1 += hi32(U.x); a2 += lo32(U.y); a3 += hi32(U.y); \
                  a4 += lo32(U.z); a5 += hi32(U.z); a6 += lo32(U.w); a7 += hi32(U.w); }
#define FMA8(D,U) { a0 = fmaf(D, lo32(U.x), a0); a1 = fmaf(D, hi32(U.x), a1); \
                    a2 = fmaf(D, lo32(U.y), a2); a3 = fmaf(D, hi32(U.y), a3); \
                    a4 = fmaf(D, lo32(U.z), a4); a5 = fmaf(D, hi32(U.z), a5); \
                    a6 = fmaf(D, lo32(U.w), a6); a7 = fmaf(D, hi32(U.w), a7); }

// ========= weight prep + bucket_cnt zero + zero-row init =========
__global__ __launch_bounds__(256) void k_prep(const float* __restrict__ Wemb,
                                              const float* __restrict__ convW,
                                              unsigned short* __restrict__ WeT,   // [64][128]
                                              unsigned short* __restrict__ WcT,   // [3][64][64]
                                              int* __restrict__ bucket_cnt,
                                              unsigned short* __restrict__ zrowA,
                                              unsigned short* __restrict__ zrowB) {
    int t = threadIdx.x;
    for (int i = t; i < NBUCK; i += 256) bucket_cnt[i] = 0;
    if (t < 64) { zrowA[t] = 0; zrowB[t] = 0; }
    for (int i = t; i < 64 * 128; i += 256) WeT[i] = 0;
    __syncthreads();
    for (int i = t; i < FIN * HH; i += 256) {
        int k = i >> 6, n = i & 63;
        WeT[n * 128 + k] = f2b(Wemb[i]);
    }
    for (int l = 0; l < 3; ++l)
        for (int i = t; i < HH * HH; i += 256) {
            int k = i >> 6, n = i & 63;
            WcT[l * 4096 + n * 64 + k] = f2b(convW[l * 4096 + i]);
        }
}

// ===== bucket place: 1024 threads/block =====
// pack: (local_dst 7b << 17) | src 17b
__global__ __launch_bounds__(1024) void k_bplace(const int* __restrict__ src,
                                                 const int* __restrict__ dst,
                                                 int* __restrict__ bucket_cnt,
                                                 unsigned int* __restrict__ upairs) {
    __shared__ int h[NBUCK];
    __shared__ int base[NBUCK];
    int t = threadIdx.x;
    for (int i = t; i < NBUCK; i += 1024) h[i] = 0;
    __syncthreads();
    int e0 = blockIdx.x * CHUNK;
    int e1 = e0 + CHUNK; if (e1 > NE) e1 = NE;
    for (int i = e0 + t; i < e1; i += 1024) atomicAdd(&h[dst[i] >> BSHIFT], 1);
    __syncthreads();
    for (int i = t; i < NBUCK; i += 1024) {
        int c = h[i];
        base[i] = c ? atomicAdd(&bucket_cnt[i], c) : 0;
    }
    __syncthreads();
    for (int i = t; i < NBUCK; i += 1024) h[i] = 0;
    __syncthreads();
    for (int i = e0 + t; i < e1; i += 1024) {
        int d = dst[i];
        int b = d >> BSHIFT;
        int pos = b * BCAP + base[b] + atomicAdd(&h[b], 1);
        upairs[pos] = ((unsigned)(d & (BSIZE - 1)) << 17) | (unsigned)src[i];
    }
}

// ===== merged: blocks < NBUCK finalize CSR (128-node buckets); rest embed+gemm0 =====
__global__ __launch_bounds__(256) void k_csr_embed(const int* __restrict__ bucket_cnt,
                                                   const unsigned int* __restrict__ upairs,
                                                   int* __restrict__ row_start,
                                                   unsigned short* __restrict__ deg16,
                                                   float* __restrict__ dinv,
                                                   int* __restrict__ csr_src,
                                                   const float* __restrict__ x,
                                                   const unsigned short* __restrict__ WeT,
                                                   const float* __restrict__ bemb,
                                                   const unsigned short* __restrict__ W0T,
                                                   unsigned short* __restrict__ g0) {
    __shared__ int degl[BSIZE];
    __shared__ int curl[BSIZE];
    __shared__ int wsum2[2];
    __shared__ __align__(16) unsigned short Xl[64 * SXE];
    int t = threadIdx.x;
    int lane = t & 63, w = t >> 6;

    if (blockIdx.x < NBUCK) {
        int b = blockIdx.x;
        int nbase = b << BSHIFT;
        int ncnt = NN - nbase; if (ncnt > BSIZE) ncnt = BSIZE;
        for (int i = t; i < BSIZE; i += 256) degl[i] = 0;
        __syncthreads();
        int p0 = b * BCAP;
        int p1 = p0 + bucket_cnt[b];
        for (int i = p0 + t; i < p1; i += 256) atomicAdd(&degl[upairs[i] >> 17], 1);
        __syncthreads();
        int vseg = 0, inc = 0;
        if (w < 2) {
            vseg = degl[w * 64 + lane];
            inc = vseg;
            for (int off = 1; off < 64; off <<= 1) {
                int n = __shfl_up(inc, off, 64);
                if (lane >= off) inc += n;
            }
            if (lane == 63) wsum2[w] = inc;
        }
        __syncthreads();
        if (w < 2) {
            int excl = (w ? wsum2[0] : 0) + inc - vseg;
            int idx = w * 64 + lane;
            int rs = p0 + excl;
            curl[idx] = rs;
            if (idx < ncnt) {
                row_start[nbase + idx] = rs;
                deg16[nbase + idx] = (unsigned short)vseg;
                dinv[nbase + idx] = rsqrtf((float)(vseg + 1));
            }
        }
        __syncthreads();
        for (int i = p0 + t; i < p1; i += 256) {
            unsigned pk = upairs[i];
            int pos = atomicAdd(&curl[pk >> 17], 1);
            csr_src[pos] = (int)(pk & 0x1FFFFu);
        }
        return;
    }

    // ---------- embed + gemm0 ----------
    int row0 = (blockIdx.x - NBUCK) * 64;
    unsigned* Xl32 = (unsigned*)Xl;
    for (int i = t; i < 64 * 25; i += 256) {
        int r = i / 25, q = i - r * 25;
        int row = row0 + r;
        uint2 pkd = {0u, 0u};
        if (row < NN) {
            float4 xv = *reinterpret_cast<const float4*>(&x[(size_t)row * FIN + q * 4]);
            pkd.x = pk2(xv.x, xv.y);
            pkd.y = pk2(xv.z, xv.w);
        }
        *reinterpret_cast<uint2*>(&Xl[r * SXE + q * 4]) = pkd;
    }
    for (int i = t; i < 64 * 18; i += 256) {
        int r = i / 18, q = i - r * 18;
        Xl32[r * 68 + 50 + q] = 0u;
    }
    __syncthreads();
    int m16 = lane & 15, g4 = lane >> 4;
    f32x4 acc[4] = {{0,0,0,0},{0,0,0,0},{0,0,0,0},{0,0,0,0}};
    const unsigned short* Arow = &Xl[(w * 16 + m16) * SXE + g4 * 8];
    #pragma unroll
    for (int kk = 0; kk < 4; ++kk) {
        short8 a = *reinterpret_cast<const short8*>(Arow + kk * 32);
        #pragma unroll
        for (int c = 0; c < 4; ++c) {
            short8 bf = *reinterpret_cast<const short8*>(&WeT[(size_t)(c * 16 + m16) * 128 + g4 * 8 + kk * 32]);
            acc[c] = __builtin_amdgcn_mfma_f32_16x16x32_bf16(a, bf, acc[c], 0, 0, 0);
        }
    }
    __syncthreads();
    unsigned short* hl = Xl;
    #pragma unroll
    for (int c = 0; c < 4; ++c) {
        int col = c * 16 + m16;
        float bb = bemb[col];
        #pragma unroll
        for (int r = 0; r < 4; ++r) {
            int rr = w * 16 + g4 * 4 + r;
            hl[rr * SH + col] = f2b(relu_f(acc[c][r] + bb));
        }
    }
    __syncthreads();
    f32x4 acc2[4] = {{0,0,0,0},{0,0,0,0},{0,0,0,0},{0,0,0,0}};
    const unsigned short* Hrow = &hl[(w * 16 + m16) * SH + g4 * 8];
    #pragma unroll
    for (int kk = 0; kk < 2; ++kk) {
        short8 a = *reinterpret_cast<const short8*>(Hrow + kk * 32);
        #pragma unroll
        for (int c = 0; c < 4; ++c) {
            short8 bf = *reinterpret_cast<const short8*>(&W0T[(size_t)(c * 16 + m16) * 64 + g4 * 8 + kk * 32]);
            acc2[c] = __builtin_amdgcn_mfma_f32_16x16x32_bf16(a, bf, acc2[c], 0, 0, 0);
        }
    }
    __syncthreads();
    #pragma unroll
    for (int c = 0; c < 4; ++c) {
        int col = c * 16 + m16;
        #pragma unroll
        for (int r = 0; r < 4; ++r) {
            int rr = w * 16 + g4 * 4 + r;
            hl[rr * SH + col] = f2b(acc2[c][r]);   // UNSCALED g0
        }
    }
    __syncthreads();
    for (int i = t; i < 64 * 8; i += 256) {
        int r = i >> 3, c8 = i & 7;
        int row = row0 + r;
        if (row < NN)
            *reinterpret_cast<uint4*>(&g0[(size_t)row * HH + c8 * 8]) =
                *reinterpret_cast<const uint4*>(&Xl[r * SH + c8 * 8]);
    }
}

// ===== agg: 16-deep load pipeline; optional 32x64 MFMA tail (2 barriers) =====
// ES=1: per-edge dinv[src] (g unscaled). GEMM=1: out = dinv*(h'@WT); else out = h'.
// Row NN of g is all-zero (safe target for masked lanes).
template <int ES, int GEMM>
__global__ __launch_bounds__(256) void k_agg(const int* __restrict__ row_start,
                                             const unsigned short* __restrict__ deg16,
                                             const int* __restrict__ csr_src,
                                             const unsigned short* __restrict__ g,
                                             const float* __restrict__ dinv,
                                             const float* __restrict__ bL,
                                             const unsigned short* __restrict__ WT,
                                             unsigned short* __restrict__ outbuf) {
    __shared__ __align__(16) unsigned short hls[GEMM ? 2 * 32 * SH : 1];
    int t = threadIdx.x;
    int lane = t & 63, w = t >> 6;
    int oct = lane >> 3;
    int sub = lane & 7;
    int v0 = blockIdx.x * 32;
    int v = v0 + w * 8 + oct;
    int st = row_start[v];
    int n = deg16[v];
    float dvv = dinv[v];
    float a0,a1,a2,a3,a4,a5,a6,a7;
    {
        uint4 u = *reinterpret_cast<const uint4*>(&g[(size_t)v * HH + sub * 8]);
        float sc = ES ? dvv : 1.f;
        a0 = sc*lo32(u.x); a1 = sc*hi32(u.x); a2 = sc*lo32(u.y); a3 = sc*hi32(u.y);
        a4 = sc*lo32(u.z); a5 = sc*hi32(u.z); a6 = sc*lo32(u.w); a7 = sc*hi32(u.w);
    }
    int sb = oct << 3;
    // preload two 8-edge windows
    int m0 = n < 8 ? n : 8;
    int m1 = (n - 8) < 8 ? (n - 8) : 8;
    int sv0 = (sub < m0) ? csr_src[st + sub] : 0;
    int sv1 = (m1 > 0 && sub < m1) ? csr_src[st + 8 + sub] : 0;
    float dl0 = 0.f, dl1 = 0.f;
    if (ES) {
        dl0 = (sub < m0) ? dinv[sv0] : 0.f;
        dl1 = (m1 > 0 && sub < m1) ? dinv[sv1] : 0.f;
    }
    for (int base = 0; base < n; base += 16) {
        int mw0 = n - base;      if (mw0 > 8) mw0 = 8;
        int mw1 = n - base - 8;  if (mw1 > 8) mw1 = 8;
        // prefetch next window pair
        int mn0 = n - base - 16; if (mn0 > 8) mn0 = 8;
        int mn1 = n - base - 24; if (mn1 > 8) mn1 = 8;
        int sv2 = 0, sv3 = 0; float dl2 = 0.f, dl3 = 0.f;
        if (mn0 > 0) {
            sv2 = (sub < mn0) ? csr_src[st + base + 16 + sub] : 0;
            if (ES) dl2 = (sub < mn0) ? dinv[sv2] : 0.f;
        }
        if (mn1 > 0) {
            sv3 = (sub < mn1) ? csr_src[st + base + 24 + sub] : 0;
            if (ES) dl3 = (sub < mn1) ? dinv[sv3] : 0.f;
        }
        // 16 row indices (masked -> zero row NN)
        int s0 = (0 < mw0) ? __shfl(sv0, sb + 0) : NN;
        int s1 = (1 < mw0) ? __shfl(sv0, sb + 1) : NN;
        int s2 = (2 < mw0) ? __shfl(sv0, sb + 2) : NN;
        int s3 = (3 < mw0) ? __shfl(sv0, sb + 3) : NN;
        int s4 = (4 < mw0) ? __shfl(sv0, sb + 4) : NN;
        int s5 = (5 < mw0) ? __shfl(sv0, sb + 5) : NN;
        int s6 = (6 < mw0) ? __shfl(sv0, sb + 6) : NN;
        int s7 = (7 < mw0) ? __shfl(sv0, sb + 7) : NN;
        int s8  = (0 < mw1) ? __shfl(sv1, sb + 0) : NN;
        int s9  = (1 < mw1) ? __shfl(sv1, sb + 1) : NN;
        int s10 = (2 < mw1) ? __shfl(sv1, sb + 2) : NN;
        int s11 = (3 < mw1) ? __shfl(sv1, sb + 3) : NN;
        int s12 = (4 < mw1) ? __shfl(sv1, sb + 4) : NN;
        int s13 = (5 < mw1) ? __shfl(sv1, sb + 5) : NN;
        int s14 = (6 < mw1) ? __shfl(sv1, sb + 6) : NN;
        int s15 = (7 < mw1) ? __shfl(sv1, sb + 7) : NN;
        // issue all 16 row loads back-to-back
        uint4 u0  = *reinterpret_cast<const uint4*>(&g[(size_t)s0  * HH + sub * 8]);
        uint4 u1  = *reinterpret_cast<const uint4*>(&g[(size_t)s1  * HH + sub * 8]);
        uint4 u2  = *reinterpret_cast<const uint4*>(&g[(size_t)s2  * HH + sub * 8]);
        uint4 u3  = *reinterpret_cast<const uint4*>(&g[(size_t)s3  * HH + sub * 8]);
        uint4 u4  = *reinterpret_cast<const uint4*>(&g[(size_t)s4  * HH + sub * 8]);
        uint4 u5  = *reinterpret_cast<const uint4*>(&g[(size_t)s5  * HH + sub * 8]);
        uint4 u6  = *reinterpret_cast<const uint4*>(&g[(size_t)s6  * HH + sub * 8]);
        uint4 u7  = *reinterpret_cast<const uint4*>(&g[(size_t)s7  * HH + sub * 8]);
        uint4 u8  = *reinterpret_cast<const uint4*>(&g[(size_t)s8  * HH + sub * 8]);
        uint4 u9  = *reinterpret_cast<const uint4*>(&g[(size_t)s9  * HH + sub * 8]);
        uint4 u10 = *reinterpret_cast<const uint4*>(&g[(size_t)s10 * HH + sub * 8]);
        uint4 u11 = *reinterpret_cast<const uint4*>(&g[(size_t)s11 * HH + sub * 8]);
        uint4 u12 = *reinterpret_cast<const uint4*>(&g[(size_t)s12 * HH + sub * 8]);
        uint4 u13 = *reinterpret_cast<const uint4*>(&g[(size_t)s13 * HH + sub * 8]);
        uint4 u14 = *reinterpret_cast<const uint4*>(&g[(size_t)s14 * HH + sub * 8]);
        uint4 u15 = *reinterpret_cast<const uint4*>(&g[(size_t)s15 * HH + sub * 8]);
        if (ES) {
            float d0 = __shfl(dl0, sb + 0), d1 = __shfl(dl0, sb + 1);
            float d2 = __shfl(dl0, sb + 2), d3 = __shfl(dl0, sb + 3);
            float d4 = __shfl(dl0, sb + 4), d5 = __shfl(dl0, sb + 5);
            float d6 = __shfl(dl0, sb + 6), d7 = __shfl(dl0, sb + 7);
            float d8  = __shfl(dl1, sb + 0), d9  = __shfl(dl1, sb + 1);
            float d10 = __shfl(dl1, sb + 2), d11 = __shfl(dl1, sb + 3);
            float d12 = __shfl(dl1, sb + 4), d13 = __shfl(dl1, sb + 5);
            float d14 = __shfl(dl1, sb + 6), d15 = __shfl(dl1, sb + 7);
            FMA8(d0, u0); FMA8(d1, u1); FMA8(d2, u2); FMA8(d3, u3);
            FMA8(d4, u4); FMA8(d5, u5); FMA8(d6, u6); FMA8(d7, u7);
            FMA8(d8, u8); FMA8(d9, u9); FMA8(d10, u10); FMA8(d11, u11);
            FMA8(d12, u12); FMA8(d13, u13); FMA8(d14, u14); FMA8(d15, u15);
        } else {
            ACC8(u0); ACC8(u1); ACC8(u2); ACC8(u3);
            ACC8(u4); ACC8(u5); ACC8(u6); ACC8(u7);
            ACC8(u8); ACC8(u9); ACC8(u10); ACC8(u11);
            ACC8(u12); ACC8(u13); ACC8(u14); ACC8(u15);
        }
        sv0 = sv2; sv1 = sv3; dl0 = dl2; dl1 = dl3;
    }
    // finalize h' = relu(dinv*a + b)
    float4 bb0 = *reinterpret_cast<const float4*>(&bL[sub * 8]);
    float4 bb1 = *reinterpret_cast<const float4*>(&bL[sub * 8 + 4]);
    uint4 hv;
    hv.x = pk2(relu_f(dvv * a0 + bb0.x), relu_f(dvv * a1 + bb0.y));
    hv.y = pk2(relu_f(dvv * a2 + bb0.z), relu_f(dvv * a3 + bb0.w));
    hv.z = pk2(relu_f(dvv * a4 + bb1.x), relu_f(dvv * a5 + bb1.y));
    hv.w = pk2(relu_f(dvv * a6 + bb1.z), relu_f(dvv * a7 + bb1.w));
    if (!GEMM) {
        *reinterpret_cast<uint4*>(&outbuf[(size_t)v * HH + sub * 8]) = hv;
        return;
    }
    // ---- 32x64 GEMM tail, 2 barriers ----
    unsigned short* hl = hls;
    unsigned short* gl = hls + 32 * SH;
    int lrow = w * 8 + oct;
    *reinterpret_cast<uint4*>(&hl[lrow * SH + sub * 8]) = hv;
    __syncthreads();
    int m16 = lane & 15, g4 = lane >> 4;
    int rb = w & 1, cbase = (w >> 1) * 2;
    f32x4 acc2[2] = {{0,0,0,0},{0,0,0,0}};
    #pragma unroll
    for (int kk = 0; kk < 2; ++kk) {
        short8 a = *reinterpret_cast<const short8*>(&hl[(rb * 16 + m16) * SH + g4 * 8 + kk * 32]);
        #pragma unroll
        for (int c = 0; c < 2; ++c) {
            short8 bf = *reinterpret_cast<const short8*>(&WT[(size_t)((cbase + c) * 16 + m16) * 64 + g4 * 8 + kk * 32]);
            acc2[c] = __builtin_amdgcn_mfma_f32_16x16x32_bf16(a, bf, acc2[c], 0, 0, 0);
        }
    }
    #pragma unroll
    for (int r = 0; r < 4; ++r) {
        int lr = rb * 16 + g4 * 4 + r;
        float dv2 = dinv[v0 + lr];
        #pragma unroll
        for (int c = 0; c < 2; ++c) {
            int col = (cbase + c) * 16 + m16;
            gl[lr * SH + col] = f2b(dv2 * acc2[c][r]);
        }
    }
    __syncthreads();
    {
        int r = t >> 3, c8 = t & 7;
        *reinterpret_cast<uint4*>(&outbuf[(size_t)(v0 + r) * HH + c8 * 8]) =
            *reinterpret_cast<const uint4*>(&gl[r * SH + c8 * 8]);
    }
}

// ===== fused pool + MLP: one block (512 thr) per graph, zero atomics =====
__global__ __launch_bounds__(512) void k_pool_mlp(const unsigned short* __restrict__ h,
                                                  const int* __restrict__ batch,
                                                  const float* __restrict__ W1, const float* __restrict__ b1,
                                                  const float* __restrict__ W2, const float* __restrict__ b2,
                                                  const float* __restrict__ W3, const float* __restrict__ b3,
                                                  float* __restrict__ out) {
    int g = blockIdx.x;
    int lo = 0, hi_s = NN;
    while (lo < hi_s) { int mid = (lo + hi_s) >> 1; if (batch[mid] < g) lo = mid + 1; else hi_s = mid; }
    int lo2 = lo, hi = NN;
    while (lo2 < hi) { int mid = (lo2 + hi) >> 1; if (batch[mid] < g + 1) lo2 = mid + 1; else hi = mid; }
    int lane = threadIdx.x & 63;
    int wave = threadIdx.x >> 6;      // 0..7
    float s = 0.f;
    for (int n = lo + wave; n < hi; n += 8) {
        s += b2f(h[(size_t)n * HH + lane]);
    }
    __shared__ float red[8][64];
    __shared__ float pv[64];
    __shared__ float tv[64];
    __shared__ float qv[32];
    red[wave][lane] = s;
    __syncthreads();
    int cnt = hi - lo;
    float invc = 1.f / (float)(cnt > 0 ? cnt : 1);
    if (threadIdx.x < 64) {
        float acc = 0.f;
        #pragma unroll
        for (int r = 0; r < 8; ++r) acc += red[r][lane];
        pv[lane] = acc * invc;
    }
    __syncthreads();
    if (threadIdx.x < 64) {
        int j = threadIdx.x;
        float s1 = b1[j];
        #pragma unroll
        for (int k = 0; k < 64; ++k) s1 = fmaf(pv[k], W1[k * 64 + j], s1);
        tv[j] = relu_f(s1);
    }
    __syncthreads();
    if (threadIdx.x < 32) {
        int j = threadIdx.x;
        float s2 = b2[j];
        #pragma unroll
        for (int k = 0; k < 64; ++k) s2 = fmaf(tv[k], W2[k * 32 + j], s2);
        qv[j] = relu_f(s2);
    }
    __syncthreads();
    if (threadIdx.x == 0) {
        float s3 = b3[0];
        #pragma unroll
        for (int k = 0; k < 32; ++k) s3 = fmaf(qv[k], W3[k], s3);
        out[g] = s3;
    }
}

extern "C" void kernel_launch(void* const* d_in, const int* in_sizes, int n_in,
                              void* d_out, int out_size, void* d_ws, size_t ws_size,
                              hipStream_t stream) {
    const float* x    = (const float*)d_in[0];
    const int*   ei   = (const int*)d_in[1];
    const int*   batch= (const int*)d_in[2];
    const float* Wemb = (const float*)d_in[3];
    const float* bemb = (const float*)d_in[4];
    const float* convW= (const float*)d_in[5];
    const float* convb= (const float*)d_in[6];
    const float* W1   = (const float*)d_in[7];
    const float* b1   = (const float*)d_in[8];
    const float* W2   = (const float*)d_in[9];
    const float* b2   = (const float*)d_in[10];
    const float* W3   = (const float*)d_in[11];
    const float* b3   = (const float*)d_in[12];
    float* out = (float*)d_out;

    auto alignup = [](size_t v) { return (v + 255) & ~(size_t)255; };
    char* p = (char*)d_ws;
    int*   row_start    = (int*)p;            p += alignup((size_t)NN * 4);
    unsigned short* deg16 = (unsigned short*)p; p += alignup((size_t)NN * 2);
    float* dinv         = (float*)p;          p += alignup((size_t)NN * 4);
    int*   bucket_cnt   = (int*)p;            p += alignup((size_t)NBUCK * 4);
    int*   csr_src      = (int*)p;            p += alignup((size_t)NBUCK * BCAP * 4);
    unsigned short* WeT = (unsigned short*)p; p += alignup((size_t)64 * 128 * 2);
    unsigned short* WcT = (unsigned short*)p; p += alignup((size_t)3 * 4096 * 2);
    unsigned short* bufA = (unsigned short*)p; p += alignup(((size_t)NN * HH + 64) * 2);
    unsigned short* bufB = (unsigned short*)p; p += alignup(((size_t)NN * HH + 64) * 2);
    // upairs aliased onto bufB (NBUCK*BCAP*4 = 8.0MB < 12.8MB); dead before first bufB write.
    unsigned int* upairs = (unsigned int*)bufB;

    const int* srcA = ei;
    const int* dstA = ei + NE;

    k_prep<<<1, 256, 0, stream>>>(Wemb, convW, WeT, WcT, bucket_cnt,
                                  bufA + (size_t)NN * HH, bufB + (size_t)NN * HH);
    k_bplace<<<NPLACE, 1024, 0, stream>>>(srcA, dstA, bucket_cnt, upairs);

    // CSR finalize (782 blocks) overlapped with embed+gemm0 (bufA = g0 unscaled)
    k_csr_embed<<<NBUCK + NBLK64, 256, 0, stream>>>(bucket_cnt, upairs, row_start, deg16, dinv,
                                                    csr_src, x, WeT, bemb, WcT + 0 * 4096, bufA);

    // layer 0: ES gather of unscaled g0, tail GEMM W1 -> bufB = g1 (pre-scaled)
    k_agg<1,1><<<AGGB, 256, 0, stream>>>(row_start, deg16, csr_src, bufA, dinv,
                                         convb + 0 * HH, WcT + 1 * 4096, bufB);
    // layer 1: pure-sum gather, tail GEMM W2 -> bufA = g2 (pre-scaled)
    k_agg<0,1><<<AGGB, 256, 0, stream>>>(row_start, deg16, csr_src, bufB, dinv,
                                         convb + 1 * HH, WcT + 2 * 4096, bufA);
    // layer 2: pure-sum gather, no tail -> bufB = h3 (activated)
    k_agg<0,0><<<AGGB, 256, 0, stream>>>(row_start, deg16, csr_src, bufA, dinv,
                                         convb + 2 * HH, nullptr, bufB);

    k_pool_mlp<<<NG, 512, 0, stream>>>(bufB, batch, W1, b1, W2, b2, W3, b3, out);
}

// Round 18
// 200.140 us; speedup vs baseline: 1.0517x; 1.0517x over previous
//
#include <hip/hip_runtime.h>
#include <hip/hip_bf16.h>

#define NN 100000
#define NE 1600000
#define NG 256
#define FIN 100
#define HH 64

#define BSHIFT 7
#define BSIZE 128
#define NBUCK ((NN + BSIZE - 1) / BSIZE)   // 782
#define BCAP 2560                          // mean 2046 + ~11 sigma
#define CHUNK 4096
#define NPLACE ((NE + CHUNK - 1) / CHUNK)  // 391

#define NBLK64 ((NN + 63) / 64)            // 1563
#define AGGB (NN / 32)                     // 3125

#define SXE 136
#define SH 72

typedef __attribute__((ext_vector_type(8))) short short8;
typedef __attribute__((ext_vector_type(4))) float f32x4;

__device__ __forceinline__ float relu_f(float x){ return x > 0.f ? x : 0.f; }
__device__ __forceinline__ unsigned short f2b(float f) {
    unsigned int u = __float_as_uint(f);
    u += 0x7fffu + ((u >> 16) & 1u);
    return (unsigned short)(u >> 16);
}
__device__ __forceinline__ unsigned pk2(float a, float b) {
    return (unsigned)f2b(a) | ((unsigned)f2b(b) << 16);
}
__device__ __forceinline__ float b2f(unsigned short h) {
    return __uint_as_float(((unsigned int)h) << 16);
}
__device__ __forceinline__ float lo32(unsigned u){ return __uint_as_float(u << 16); }
__device__ __forceinline__ float hi32(unsigned u){ return __uint_as_float(u & 0xffff0000u); }

#define ACC8(U) { a0 += lo32(U.x); a1 += hi32(U.x); a2 += lo32(U.y); a3 += hi32(U.y); \
                  a4 += lo32(U.z); a5 += hi32(U.z); a6 += lo32(U.w); a7 += hi32(U.w); }
#define FMA8(D,U) { a0 = fmaf(D, lo32(U.x), a0); a1 = fmaf(D, hi32(U.x), a1); \
                    a2 = fmaf(D, lo32(U.y), a2); a3 = fmaf(D, hi32(U.y), a3); \
                    a4 = fmaf(D, lo32(U.z), a4); a5 = fmaf(D, hi32(U.z), a5); \
                    a6 = fmaf(D, lo32(U.w), a6); a7 = fmaf(D, hi32(U.w), a7); }

// ========= weight prep + bucket_cnt zero + zero-row init =========
__global__ __launch_bounds__(256) void k_prep(const float* __restrict__ Wemb,
                                              const float* __restrict__ convW,
                                              unsigned short* __restrict__ WeT,   // [64][128]
                                              unsigned short* __restrict__ WcT,   // [3][64][64]
                                              int* __restrict__ bucket_cnt,
                                              unsigned short* __restrict__ zrowA,
                                              unsigned short* __restrict__ zrowB) {
    int t = threadIdx.x;
    for (int i = t; i < NBUCK; i += 256) bucket_cnt[i] = 0;
    if (t < 64) { zrowA[t] = 0; zrowB[t] = 0; }
    for (int i = t; i < 64 * 128; i += 256) WeT[i] = 0;
    __syncthreads();
    for (int i = t; i < FIN * HH; i += 256) {
        int k = i >> 6, n = i & 63;
        WeT[n * 128 + k] = f2b(Wemb[i]);
    }
    for (int l = 0; l < 3; ++l)
        for (int i = t; i < HH * HH; i += 256) {
            int k = i >> 6, n = i & 63;
            WcT[l * 4096 + n * 64 + k] = f2b(convW[l * 4096 + i]);
        }
}

// ===== bucket place: 1024 threads/block =====
// pack: (local_dst 7b << 17) | src 17b
__global__ __launch_bounds__(1024) void k_bplace(const int* __restrict__ src,
                                                 const int* __restrict__ dst,
                                                 int* __restrict__ bucket_cnt,
                                                 unsigned int* __restrict__ upairs) {
    __shared__ int h[NBUCK];
    __shared__ int base[NBUCK];
    int t = threadIdx.x;
    for (int i = t; i < NBUCK; i += 1024) h[i] = 0;
    __syncthreads();
    int e0 = blockIdx.x * CHUNK;
    int e1 = e0 + CHUNK; if (e1 > NE) e1 = NE;
    for (int i = e0 + t; i < e1; i += 1024) atomicAdd(&h[dst[i] >> BSHIFT], 1);
    __syncthreads();
    for (int i = t; i < NBUCK; i += 1024) {
        int c = h[i];
        base[i] = c ? atomicAdd(&bucket_cnt[i], c) : 0;
    }
    __syncthreads();
    for (int i = t; i < NBUCK; i += 1024) h[i] = 0;
    __syncthreads();
    for (int i = e0 + t; i < e1; i += 1024) {
        int d = dst[i];
        int b = d >> BSHIFT;
        int pos = b * BCAP + base[b] + atomicAdd(&h[b], 1);
        upairs[pos] = ((unsigned)(d & (BSIZE - 1)) << 17) | (unsigned)src[i];
    }
}

// ===== merged: blocks < NBUCK finalize CSR (128-node buckets); rest embed+gemm0 =====
__global__ __launch_bounds__(256) void k_csr_embed(const int* __restrict__ bucket_cnt,
                                                   const unsigned int* __restrict__ upairs,
                                                   int* __restrict__ row_start,
                                                   unsigned short* __restrict__ deg16,
                                                   float* __restrict__ dinv,
                                                   int* __restrict__ csr_src,
                                                   const float* __restrict__ x,
                                                   const unsigned short* __restrict__ WeT,
                                                   const float* __restrict__ bemb,
                                                   const unsigned short* __restrict__ W0T,
                                                   unsigned short* __restrict__ g0) {
    __shared__ int degl[BSIZE];
    __shared__ int curl[BSIZE];
    __shared__ int wsum2[2];
    __shared__ __align__(16) unsigned short Xl[64 * SXE];
    int t = threadIdx.x;
    int lane = t & 63, w = t >> 6;

    if (blockIdx.x < NBUCK) {
        // ---------- CSR finalize (128-node bucket, ~2048 edges) ----------
        int b = blockIdx.x;
        int nbase = b << BSHIFT;
        int ncnt = NN - nbase; if (ncnt > BSIZE) ncnt = BSIZE;
        for (int i = t; i < BSIZE; i += 256) degl[i] = 0;
        __syncthreads();
        int p0 = b * BCAP;
        int p1 = p0 + bucket_cnt[b];
        for (int i = p0 + t; i < p1; i += 256) atomicAdd(&degl[upairs[i] >> 17], 1);
        __syncthreads();
        int vseg = 0, inc = 0;
        if (w < 2) {
            vseg = degl[w * 64 + lane];
            inc = vseg;
            for (int off = 1; off < 64; off <<= 1) {
                int n = __shfl_up(inc, off, 64);
                if (lane >= off) inc += n;
            }
            if (lane == 63) wsum2[w] = inc;
        }
        __syncthreads();
        if (w < 2) {
            int excl = (w ? wsum2[0] : 0) + inc - vseg;
            int idx = w * 64 + lane;
            int rs = p0 + excl;
            curl[idx] = rs;
            if (idx < ncnt) {
                row_start[nbase + idx] = rs;
                deg16[nbase + idx] = (unsigned short)vseg;
                dinv[nbase + idx] = rsqrtf((float)(vseg + 1));
            }
        }
        __syncthreads();
        for (int i = p0 + t; i < p1; i += 256) {
            unsigned pk = upairs[i];
            int pos = atomicAdd(&curl[pk >> 17], 1);
            csr_src[pos] = (int)(pk & 0x1FFFFu);
        }
        return;
    }

    // ---------- embed + gemm0 ----------
    int row0 = (blockIdx.x - NBUCK) * 64;
    unsigned* Xl32 = (unsigned*)Xl;
    for (int i = t; i < 64 * 25; i += 256) {
        int r = i / 25, q = i - r * 25;
        int row = row0 + r;
        uint2 pkd = {0u, 0u};
        if (row < NN) {
            float4 xv = *reinterpret_cast<const float4*>(&x[(size_t)row * FIN + q * 4]);
            pkd.x = pk2(xv.x, xv.y);
            pkd.y = pk2(xv.z, xv.w);
        }
        *reinterpret_cast<uint2*>(&Xl[r * SXE + q * 4]) = pkd;
    }
    for (int i = t; i < 64 * 18; i += 256) {
        int r = i / 18, q = i - r * 18;
        Xl32[r * 68 + 50 + q] = 0u;
    }
    __syncthreads();
    int m16 = lane & 15, g4 = lane >> 4;
    f32x4 acc[4] = {{0,0,0,0},{0,0,0,0},{0,0,0,0},{0,0,0,0}};
    const unsigned short* Arow = &Xl[(w * 16 + m16) * SXE + g4 * 8];
    #pragma unroll
    for (int kk = 0; kk < 4; ++kk) {
        short8 a = *reinterpret_cast<const short8*>(Arow + kk * 32);
        #pragma unroll
        for (int c = 0; c < 4; ++c) {
            short8 bf = *reinterpret_cast<const short8*>(&WeT[(size_t)(c * 16 + m16) * 128 + g4 * 8 + kk * 32]);
            acc[c] = __builtin_amdgcn_mfma_f32_16x16x32_bf16(a, bf, acc[c], 0, 0, 0);
        }
    }
    __syncthreads();
    unsigned short* hl = Xl;
    #pragma unroll
    for (int c = 0; c < 4; ++c) {
        int col = c * 16 + m16;
        float bb = bemb[col];
        #pragma unroll
        for (int r = 0; r < 4; ++r) {
            int rr = w * 16 + g4 * 4 + r;
            hl[rr * SH + col] = f2b(relu_f(acc[c][r] + bb));
        }
    }
    __syncthreads();
    f32x4 acc2[4] = {{0,0,0,0},{0,0,0,0},{0,0,0,0},{0,0,0,0}};
    const unsigned short* Hrow = &hl[(w * 16 + m16) * SH + g4 * 8];
    #pragma unroll
    for (int kk = 0; kk < 2; ++kk) {
        short8 a = *reinterpret_cast<const short8*>(Hrow + kk * 32);
        #pragma unroll
        for (int c = 0; c < 4; ++c) {
            short8 bf = *reinterpret_cast<const short8*>(&W0T[(size_t)(c * 16 + m16) * 64 + g4 * 8 + kk * 32]);
            acc2[c] = __builtin_amdgcn_mfma_f32_16x16x32_bf16(a, bf, acc2[c], 0, 0, 0);
        }
    }
    __syncthreads();
    #pragma unroll
    for (int c = 0; c < 4; ++c) {
        int col = c * 16 + m16;
        #pragma unroll
        for (int r = 0; r < 4; ++r) {
            int rr = w * 16 + g4 * 4 + r;
            hl[rr * SH + col] = f2b(acc2[c][r]);   // UNSCALED g0
        }
    }
    __syncthreads();
    for (int i = t; i < 64 * 8; i += 256) {
        int r = i >> 3, c8 = i & 7;
        int row = row0 + r;
        if (row < NN)
            *reinterpret_cast<uint4*>(&g0[(size_t)row * HH + c8 * 8]) =
                *reinterpret_cast<const uint4*>(&Xl[r * SH + c8 * 8]);
    }
}

// ===== agg: 8-deep load issue + sv prefetch; optional 32x64 MFMA tail (2 barriers) =====
// ES=1: per-edge dinv[src] (g unscaled). GEMM=1: out = dinv*(h'@WT); else out = h'.
// Row NN of g is all-zero (safe target for masked lanes).
template <int ES, int GEMM>
__global__ __launch_bounds__(256) void k_agg(const int* __restrict__ row_start,
                                             const unsigned short* __restrict__ deg16,
                                             const int* __restrict__ csr_src,
                                             const unsigned short* __restrict__ g,
                                             const float* __restrict__ dinv,
                                             const float* __restrict__ bL,
                                             const unsigned short* __restrict__ WT,
                                             unsigned short* __restrict__ outbuf) {
    __shared__ __align__(16) unsigned short hls[GEMM ? 2 * 32 * SH : 1];
    int t = threadIdx.x;
    int lane = t & 63, w = t >> 6;
    int oct = lane >> 3;
    int sub = lane & 7;
    int v0 = blockIdx.x * 32;
    int v = v0 + w * 8 + oct;
    int st = row_start[v];
    int n = deg16[v];
    float dvv = dinv[v];
    float a0,a1,a2,a3,a4,a5,a6,a7;
    {
        uint4 u = *reinterpret_cast<const uint4*>(&g[(size_t)v * HH + sub * 8]);
        float sc = ES ? dvv : 1.f;
        a0 = sc*lo32(u.x); a1 = sc*hi32(u.x); a2 = sc*lo32(u.y); a3 = sc*hi32(u.y);
        a4 = sc*lo32(u.z); a5 = sc*hi32(u.z); a6 = sc*lo32(u.w); a7 = sc*hi32(u.w);
    }
    int sb = oct << 3;
    int m0 = n < 8 ? n : 8;
    int sv = (sub < m0) ? csr_src[st + sub] : 0;
    float dl = 0.f;
    if (ES) dl = (sub < m0) ? dinv[sv] : 0.f;
    for (int base = 0; base < n; base += 8) {
        int mw = n - base; if (mw > 8) mw = 8;
        int mn = n - base - 8; if (mn > 8) mn = 8;
        int svn = 0; float dln = 0.f;
        if (mn > 0) {
            svn = (sub < mn) ? csr_src[st + base + 8 + sub] : 0;
            if (ES) dln = (sub < mn) ? dinv[svn] : 0.f;
        }
        int s0 = (0 < mw) ? __shfl(sv, sb + 0) : NN;
        int s1 = (1 < mw) ? __shfl(sv, sb + 1) : NN;
        int s2 = (2 < mw) ? __shfl(sv, sb + 2) : NN;
        int s3 = (3 < mw) ? __shfl(sv, sb + 3) : NN;
        int s4 = (4 < mw) ? __shfl(sv, sb + 4) : NN;
        int s5 = (5 < mw) ? __shfl(sv, sb + 5) : NN;
        int s6 = (6 < mw) ? __shfl(sv, sb + 6) : NN;
        int s7 = (7 < mw) ? __shfl(sv, sb + 7) : NN;
        uint4 u0 = *reinterpret_cast<const uint4*>(&g[(size_t)s0 * HH + sub * 8]);
        uint4 u1 = *reinterpret_cast<const uint4*>(&g[(size_t)s1 * HH + sub * 8]);
        uint4 u2 = *reinterpret_cast<const uint4*>(&g[(size_t)s2 * HH + sub * 8]);
        uint4 u3 = *reinterpret_cast<const uint4*>(&g[(size_t)s3 * HH + sub * 8]);
        uint4 u4 = *reinterpret_cast<const uint4*>(&g[(size_t)s4 * HH + sub * 8]);
        uint4 u5 = *reinterpret_cast<const uint4*>(&g[(size_t)s5 * HH + sub * 8]);
        uint4 u6 = *reinterpret_cast<const uint4*>(&g[(size_t)s6 * HH + sub * 8]);
        uint4 u7 = *reinterpret_cast<const uint4*>(&g[(size_t)s7 * HH + sub * 8]);
        if (ES) {
            float d0 = __shfl(dl, sb + 0), d1 = __shfl(dl, sb + 1);
            float d2 = __shfl(dl, sb + 2), d3 = __shfl(dl, sb + 3);
            float d4 = __shfl(dl, sb + 4), d5 = __shfl(dl, sb + 5);
            float d6 = __shfl(dl, sb + 6), d7 = __shfl(dl, sb + 7);
            FMA8(d0, u0); FMA8(d1, u1); FMA8(d2, u2); FMA8(d3, u3);
            FMA8(d4, u4); FMA8(d5, u5); FMA8(d6, u6); FMA8(d7, u7);
        } else {
            ACC8(u0); ACC8(u1); ACC8(u2); ACC8(u3);
            ACC8(u4); ACC8(u5); ACC8(u6); ACC8(u7);
        }
        sv = svn; dl = dln;
    }
    // finalize h' = relu(dinv*a + b)
    float4 bb0 = *reinterpret_cast<const float4*>(&bL[sub * 8]);
    float4 bb1 = *reinterpret_cast<const float4*>(&bL[sub * 8 + 4]);
    uint4 hv;
    hv.x = pk2(relu_f(dvv * a0 + bb0.x), relu_f(dvv * a1 + bb0.y));
    hv.y = pk2(relu_f(dvv * a2 + bb0.z), relu_f(dvv * a3 + bb0.w));
    hv.z = pk2(relu_f(dvv * a4 + bb1.x), relu_f(dvv * a5 + bb1.y));
    hv.w = pk2(relu_f(dvv * a6 + bb1.z), relu_f(dvv * a7 + bb1.w));
    if (!GEMM) {
        *reinterpret_cast<uint4*>(&outbuf[(size_t)v * HH + sub * 8]) = hv;
        return;
    }
    // ---- 32x64 GEMM tail, 2 barriers ----
    unsigned short* hl = hls;
    unsigned short* gl = hls + 32 * SH;
    int lrow = w * 8 + oct;
    *reinterpret_cast<uint4*>(&hl[lrow * SH + sub * 8]) = hv;
    __syncthreads();
    int m16 = lane & 15, g4 = lane >> 4;
    int rb = w & 1, cbase = (w >> 1) * 2;
    f32x4 acc2[2] = {{0,0,0,0},{0,0,0,0}};
    #pragma unroll
    for (int kk = 0; kk < 2; ++kk) {
        short8 a = *reinterpret_cast<const short8*>(&hl[(rb * 16 + m16) * SH + g4 * 8 + kk * 32]);
        #pragma unroll
        for (int c = 0; c < 2; ++c) {
            short8 bf = *reinterpret_cast<const short8*>(&WT[(size_t)((cbase + c) * 16 + m16) * 64 + g4 * 8 + kk * 32]);
            acc2[c] = __builtin_amdgcn_mfma_f32_16x16x32_bf16(a, bf, acc2[c], 0, 0, 0);
        }
    }
    #pragma unroll
    for (int r = 0; r < 4; ++r) {
        int lr = rb * 16 + g4 * 4 + r;
        float dv2 = dinv[v0 + lr];
        #pragma unroll
        for (int c = 0; c < 2; ++c) {
            int col = (cbase + c) * 16 + m16;
            gl[lr * SH + col] = f2b(dv2 * acc2[c][r]);
        }
    }
    __syncthreads();
    {
        int r = t >> 3, c8 = t & 7;
        *reinterpret_cast<uint4*>(&outbuf[(size_t)(v0 + r) * HH + c8 * 8]) =
            *reinterpret_cast<const uint4*>(&gl[r * SH + c8 * 8]);
    }
}

// ===== fused pool + MLP: one block (512 thr) per graph, zero atomics =====
__global__ __launch_bounds__(512) void k_pool_mlp(const unsigned short* __restrict__ h,
                                                  const int* __restrict__ batch,
                                                  const float* __restrict__ W1, const float* __restrict__ b1,
                                                  const float* __restrict__ W2, const float* __restrict__ b2,
                                                  const float* __restrict__ W3, const float* __restrict__ b3,
                                                  float* __restrict__ out) {
    int g = blockIdx.x;
    int lo = 0, hi_s = NN;
    while (lo < hi_s) { int mid = (lo + hi_s) >> 1; if (batch[mid] < g) lo = mid + 1; else hi_s = mid; }
    int lo2 = lo, hi = NN;
    while (lo2 < hi) { int mid = (lo2 + hi) >> 1; if (batch[mid] < g + 1) lo2 = mid + 1; else hi = mid; }
    int lane = threadIdx.x & 63;
    int wave = threadIdx.x >> 6;      // 0..7
    float s = 0.f;
    for (int n = lo + wave; n < hi; n += 8) {
        s += b2f(h[(size_t)n * HH + lane]);
    }
    __shared__ float red[8][64];
    __shared__ float pv[64];
    __shared__ float tv[64];
    __shared__ float qv[32];
    red[wave][lane] = s;
    __syncthreads();
    int cnt = hi - lo;
    float invc = 1.f / (float)(cnt > 0 ? cnt : 1);
    if (threadIdx.x < 64) {
        float acc = 0.f;
        #pragma unroll
        for (int r = 0; r < 8; ++r) acc += red[r][lane];
        pv[lane] = acc * invc;
    }
    __syncthreads();
    if (threadIdx.x < 64) {
        int j = threadIdx.x;
        float s1 = b1[j];
        #pragma unroll
        for (int k = 0; k < 64; ++k) s1 = fmaf(pv[k], W1[k * 64 + j], s1);
        tv[j] = relu_f(s1);
    }
    __syncthreads();
    if (threadIdx.x < 32) {
        int j = threadIdx.x;
        float s2 = b2[j];
        #pragma unroll
        for (int k = 0; k < 64; ++k) s2 = fmaf(tv[k], W2[k * 32 + j], s2);
        qv[j] = relu_f(s2);
    }
    __syncthreads();
    if (threadIdx.x == 0) {
        float s3 = b3[0];
        #pragma unroll
        for (int k = 0; k < 32; ++k) s3 = fmaf(qv[k], W3[k], s3);
        out[g] = s3;
    }
}

extern "C" void kernel_launch(void* const* d_in, const int* in_sizes, int n_in,
                              void* d_out, int out_size, void* d_ws, size_t ws_size,
                              hipStream_t stream) {
    const float* x    = (const float*)d_in[0];
    const int*   ei   = (const int*)d_in[1];
    const int*   batch= (const int*)d_in[2];
    const float* Wemb = (const float*)d_in[3];
    const float* bemb = (const float*)d_in[4];
    const float* convW= (const float*)d_in[5];
    const float* convb= (const float*)d_in[6];
    const float* W1   = (const float*)d_in[7];
    const float* b1   = (const float*)d_in[8];
    const float* W2   = (const float*)d_in[9];
    const float* b2   = (const float*)d_in[10];
    const float* W3   = (const float*)d_in[11];
    const float* b3   = (const float*)d_in[12];
    float* out = (float*)d_out;

    auto alignup = [](size_t v) { return (v + 255) & ~(size_t)255; };
    char* p = (char*)d_ws;
    int*   row_start    = (int*)p;            p += alignup((size_t)NN * 4);
    unsigned short* deg16 = (unsigned short*)p; p += alignup((size_t)NN * 2);
    float* dinv         = (float*)p;          p += alignup((size_t)NN * 4);
    int*   bucket_cnt   = (int*)p;            p += alignup((size_t)NBUCK * 4);
    int*   csr_src      = (int*)p;            p += alignup((size_t)NBUCK * BCAP * 4);
    unsigned short* WeT = (unsigned short*)p; p += alignup((size_t)64 * 128 * 2);
    unsigned short* WcT = (unsigned short*)p; p += alignup((size_t)3 * 4096 * 2);
    unsigned short* bufA = (unsigned short*)p; p += alignup(((size_t)NN * HH + 64) * 2);
    unsigned short* bufB = (unsigned short*)p; p += alignup(((size_t)NN * HH + 64) * 2);
    // upairs aliased onto bufB (NBUCK*BCAP*4 = 8.0MB < 12.8MB); dead before first bufB write.
    unsigned int* upairs = (unsigned int*)bufB;

    const int* srcA = ei;
    const int* dstA = ei + NE;

    k_prep<<<1, 256, 0, stream>>>(Wemb, convW, WeT, WcT, bucket_cnt,
                                  bufA + (size_t)NN * HH, bufB + (size_t)NN * HH);
    k_bplace<<<NPLACE, 1024, 0, stream>>>(srcA, dstA, bucket_cnt, upairs);

    // CSR finalize (782 blocks) overlapped with embed+gemm0 (bufA = g0 unscaled)
    k_csr_embed<<<NBUCK + NBLK64, 256, 0, stream>>>(bucket_cnt, upairs, row_start, deg16, dinv,
                                                    csr_src, x, WeT, bemb, WcT + 0 * 4096, bufA);

    // layer 0: ES gather of unscaled g0, tail GEMM W1 -> bufB = g1 (pre-scaled)
    k_agg<1,1><<<AGGB, 256, 0, stream>>>(row_start, deg16, csr_src, bufA, dinv,
                                         convb + 0 * HH, WcT + 1 * 4096, bufB);
    // layer 1: pure-sum gather, tail GEMM W2 -> bufA = g2 (pre-scaled)
    k_agg<0,1><<<AGGB, 256, 0, stream>>>(row_start, deg16, csr_src, bufB, dinv,
                                         convb + 1 * HH, WcT + 2 * 4096, bufA);
    // layer 2: pure-sum gather, no tail -> bufB = h3 (activated)
    k_agg<0,0><<<AGGB, 256, 0, stream>>>(row_start, deg16, csr_src, bufA, dinv,
                                         convb + 2 * HH, nullptr, bufB);

    k_pool_mlp<<<NG, 512, 0, stream>>>(bufB, batch, W1, b1, W2, b2, W3, b3, out);
}